// Round 13
// baseline (358.578 us; speedup 1.0000x reference)
//
#include <hip/hip_runtime.h>

constexpr int B  = 8,  P = 50, N = 128, M = 128;
constexpr int EMB = 128, H = 8, D = 16;
constexpr int NE = 8;
constexpr int HD = H * D;        // 128
constexpr int E1 = EMB + 1;      // 129
constexpr int BP = B * P;        // 400
constexpr int T  = BP * N;       // 51200 tokens

// ---------------------------------------------------------------------------
// K1: projections, r22 = r12 + LDS UNION FIX. grid (400, 3), block 256.
//   y==0: q = nodes @ Wq                       (Kd=128)
//   y==1: k,v = routes @ {Wk,Wv} merged        (Kd=129, X staged once)
//   y==2: prep (We'/b' collapse, zero importance+ticket)
// r12 bug: branch-scoped __shared__ SUMMED (16.9+25.3=41.5 KB -> 3 blk/CU,
// occupancy 8.7%, VALUBusy 36%). Fix: one union = 25.3 KB -> 6 blk/CU.
// ---------------------------------------------------------------------------
__global__ __launch_bounds__(256) void proj_kernel(
    const float* __restrict__ nodes,  // [T][128]
    const float* __restrict__ routes, // [T][129]
    const float* __restrict__ Wq, const float* __restrict__ Wk,
    const float* __restrict__ Wv,
    float* __restrict__ qo, float* __restrict__ ko, float* __restrict__ vo,
    const float* __restrict__ We, const float* __restrict__ be,
    const float* __restrict__ Wf,
    float* __restrict__ Wep, float* __restrict__ bpv,
    float* __restrict__ importance, unsigned* __restrict__ ticket) {
    const int mat = blockIdx.y;

    // ONE shared allocation for all paths (union: max, not sum — r12 fix)
    __shared__ union ShU {
        struct { float XT[2][8][132], WK[2][8][132], WV[2][8][132]; } kv;
        struct { float XT[2][8][132], WS[2][8][132]; } q;
    } sh;

    if (mat == 2) {                   // ---- folded prep ----
        const int e = blockIdx.x;
        if (e >= NE) return;
        const int f = threadIdx.x;
        if (f < HD) {
            float a = 0.f;
            const long base = ((long)e * HD + f) * E1;
            for (int o = 0; o < E1; ++o) a += We[base + o] * Wf[o];
            Wep[e * HD + f] = a;
        } else if (f == HD) {
            float b = 0.f;
            for (int o = 0; o < E1; ++o) b += be[(long)e * E1 + o] * Wf[o];
            bpv[e] = b;
        }
        if (e == 0) {
            if (f >= 140 && f < 140 + NE) importance[f - 140] = 0.f;
            if (f == 150) *ticket = 0u;
        }
        return;
    }

    const int row0 = blockIdx.x * 128;
    const int tid  = threadIdx.x;
    const int tr   = tid >> 4;        // 0..15
    const int tc   = tid & 15;        // 0..15
    const int xkx = tid & 7, xrr = tid >> 3;          // +i*32 rows
    const int wkx = tid >> 5, wc4 = (tid & 31) * 4;

    if (mat == 1) {                   // ---- merged k+v (X = routes) ----
        const int Kd  = E1;           // 129
        const int nit = (Kd + 7) >> 3;  // 17

        float acck[8][8], accv[8][8];
        #pragma unroll
        for (int i = 0; i < 8; ++i)
            #pragma unroll
            for (int j = 0; j < 8; ++j) { acck[i][j] = 0.f; accv[i][j] = 0.f; }

        float xr[4];
        float4 wrk, wrv;

        {   // prologue: fetch tile 0 (k indices 0..7 all < 129)
            #pragma unroll
            for (int i = 0; i < 4; ++i)
                xr[i] = routes[(long)(row0 + xrr + i * 32) * Kd + xkx];
            wrk = *(const float4*)&Wk[(long)wkx * HD + wc4];
            wrv = *(const float4*)&Wv[(long)wkx * HD + wc4];
            #pragma unroll
            for (int i = 0; i < 4; ++i) sh.kv.XT[0][xkx][xrr + i * 32] = xr[i];
            *(float4*)&sh.kv.WK[0][wkx][wc4] = wrk;
            *(float4*)&sh.kv.WV[0][wkx][wc4] = wrv;
        }
        __syncthreads();

        for (int it = 0; it < nit; ++it) {
            const int buf = it & 1;
            if (it + 1 < nit) {
                const int kk = (it + 1) * 8;
                #pragma unroll
                for (int i = 0; i < 4; ++i) {
                    int kg = kk + xkx;
                    xr[i] = (kg < Kd) ? routes[(long)(row0 + xrr + i * 32) * Kd + kg] : 0.f;
                }
                int kg = kk + wkx;
                if (kg < Kd) {
                    wrk = *(const float4*)&Wk[(long)kg * HD + wc4];
                    wrv = *(const float4*)&Wv[(long)kg * HD + wc4];
                } else {
                    wrk = make_float4(0.f, 0.f, 0.f, 0.f);
                    wrv = make_float4(0.f, 0.f, 0.f, 0.f);
                }
            }

            #pragma unroll
            for (int k = 0; k < 8; ++k) {
                float4 xa = *(const float4*)&sh.kv.XT[buf][k][tr * 4];
                float4 xb = *(const float4*)&sh.kv.XT[buf][k][64 + tr * 4];
                float4 ka = *(const float4*)&sh.kv.WK[buf][k][tc * 4];
                float4 kb = *(const float4*)&sh.kv.WK[buf][k][64 + tc * 4];
                float4 va = *(const float4*)&sh.kv.WV[buf][k][tc * 4];
                float4 vb = *(const float4*)&sh.kv.WV[buf][k][64 + tc * 4];
                float xv[8]  = {xa.x, xa.y, xa.z, xa.w, xb.x, xb.y, xb.z, xb.w};
                float wk8[8] = {ka.x, ka.y, ka.z, ka.w, kb.x, kb.y, kb.z, kb.w};
                float wv8[8] = {va.x, va.y, va.z, va.w, vb.x, vb.y, vb.z, vb.w};
                #pragma unroll
                for (int i = 0; i < 8; ++i)
                    #pragma unroll
                    for (int j = 0; j < 8; ++j) {
                        acck[i][j] += xv[i] * wk8[j];
                        accv[i][j] += xv[i] * wv8[j];
                    }
            }

            if (it + 1 < nit) {
                const int nb = buf ^ 1;
                #pragma unroll
                for (int i = 0; i < 4; ++i) sh.kv.XT[nb][xkx][xrr + i * 32] = xr[i];
                *(float4*)&sh.kv.WK[nb][wkx][wc4] = wrk;
                *(float4*)&sh.kv.WV[nb][wkx][wc4] = wrv;
            }
            __syncthreads();
        }

        #pragma unroll
        for (int i = 0; i < 8; ++i) {
            int r = row0 + (i < 4 ? 0 : 64) + tr * 4 + (i & 3);
            float4 k0 = make_float4(acck[i][0], acck[i][1], acck[i][2], acck[i][3]);
            float4 k1 = make_float4(acck[i][4], acck[i][5], acck[i][6], acck[i][7]);
            float4 v0 = make_float4(accv[i][0], accv[i][1], accv[i][2], accv[i][3]);
            float4 v1 = make_float4(accv[i][4], accv[i][5], accv[i][6], accv[i][7]);
            *(float4*)&ko[(long)r * HD + tc * 4]      = k0;
            *(float4*)&ko[(long)r * HD + 64 + tc * 4] = k1;
            *(float4*)&vo[(long)r * HD + tc * 4]      = v0;
            *(float4*)&vo[(long)r * HD + 64 + tc * 4] = v1;
        }
        return;
    }

    // ---- mat == 0: q = nodes @ Wq (Kd=128) ----
    {
        const int Kd  = EMB;          // 128
        const int nit = Kd >> 3;      // 16

        float acc[8][8];
        #pragma unroll
        for (int i = 0; i < 8; ++i)
            #pragma unroll
            for (int j = 0; j < 8; ++j) acc[i][j] = 0.f;

        float xr[4];
        float4 wr;

        {   // prologue: fetch tile 0
            #pragma unroll
            for (int i = 0; i < 4; ++i)
                xr[i] = nodes[(long)(row0 + xrr + i * 32) * Kd + xkx];
            wr = *(const float4*)&Wq[(long)wkx * HD + wc4];
            #pragma unroll
            for (int i = 0; i < 4; ++i) sh.q.XT[0][xkx][xrr + i * 32] = xr[i];
            *(float4*)&sh.q.WS[0][wkx][wc4] = wr;
        }
        __syncthreads();

        for (int it = 0; it < nit; ++it) {
            const int buf = it & 1;
            if (it + 1 < nit) {
                const int kk = (it + 1) * 8;
                #pragma unroll
                for (int i = 0; i < 4; ++i)
                    xr[i] = nodes[(long)(row0 + xrr + i * 32) * Kd + kk + xkx];
                wr = *(const float4*)&Wq[(long)(kk + wkx) * HD + wc4];
            }

            #pragma unroll
            for (int k = 0; k < 8; ++k) {
                float4 xa = *(const float4*)&sh.q.XT[buf][k][tr * 4];
                float4 xb = *(const float4*)&sh.q.XT[buf][k][64 + tr * 4];
                float4 wa = *(const float4*)&sh.q.WS[buf][k][tc * 4];
                float4 wb = *(const float4*)&sh.q.WS[buf][k][64 + tc * 4];
                float xv[8]  = {xa.x, xa.y, xa.z, xa.w, xb.x, xb.y, xb.z, xb.w};
                float wvv[8] = {wa.x, wa.y, wa.z, wa.w, wb.x, wb.y, wb.z, wb.w};
                #pragma unroll
                for (int i = 0; i < 8; ++i)
                    #pragma unroll
                    for (int j = 0; j < 8; ++j) acc[i][j] += xv[i] * wvv[j];
            }

            if (it + 1 < nit) {
                const int nb = buf ^ 1;
                #pragma unroll
                for (int i = 0; i < 4; ++i) sh.q.XT[nb][xkx][xrr + i * 32] = xr[i];
                *(float4*)&sh.q.WS[nb][wkx][wc4] = wr;
            }
            __syncthreads();
        }

        #pragma unroll
        for (int i = 0; i < 8; ++i) {
            int r = row0 + (i < 4 ? 0 : 64) + tr * 4 + (i & 3);
            float4 o0 = make_float4(acc[i][0], acc[i][1], acc[i][2], acc[i][3]);
            float4 o1 = make_float4(acc[i][4], acc[i][5], acc[i][6], acc[i][7]);
            *(float4*)&qo[(long)r * HD + tc * 4]      = o0;
            *(float4*)&qo[(long)r * HD + 64 + tc * 4] = o1;
        }
    }
}

// ---------------------------------------------------------------------------
// K2: masked attention per (bp, head). grid (BP, 8), block 64 (1 wave).
// r11-EXACT (93.2 us, reproduced twice). FROZEN — 9 variants lost. h MUST
// stay blockIdx-derived (r10: scalar v-load path). Transposed stores.
// ---------------------------------------------------------------------------
__global__ __launch_bounds__(64) void attn_kernel(
    const float* __restrict__ qbuf,   // [T][128]
    const float* __restrict__ kbuf,   // [T][128]
    const float* __restrict__ vbuf,   // [T][128]
    const float* __restrict__ rmask,  // [BP*N][M]
    const float* __restrict__ ninf,   // [BP*N]
    float* __restrict__ xcatT) {      // [BP][HD][N] transposed!
    const int bp  = blockIdx.x;
    const int h   = blockIdx.y;       // MUST be blockIdx-derived (r10!)
    const int tid = threadIdx.x;

    __shared__ float kh[M][D];        // 8 KB (k only)

    #pragma unroll
    for (int i = 0; i < 8; ++i) {
        int e = tid + i * 64;         // f4 index 0..511
        int r = e >> 2, c4 = (e & 3) * 4;
        *(float4*)&kh[r][c4] = *(const float4*)&kbuf[((long)bp * M + r) * HD + h * D + c4];
    }
    __syncthreads();

    const long t0 = (long)bp * N + tid, t1 = t0 + 64;

    float qr0[16], qr1[16];
    {
        const float4* q0 = (const float4*)&qbuf[t0 * HD + h * D];
        const float4* q1 = (const float4*)&qbuf[t1 * HD + h * D];
        #pragma unroll
        for (int i = 0; i < 4; ++i) {
            float4 a = q0[i], b = q1[i];
            qr0[i*4+0] = a.x*0.25f; qr0[i*4+1] = a.y*0.25f;
            qr0[i*4+2] = a.z*0.25f; qr0[i*4+3] = a.w*0.25f;
            qr1[i*4+0] = b.x*0.25f; qr1[i*4+1] = b.y*0.25f;
            qr1[i*4+2] = b.z*0.25f; qr1[i*4+3] = b.w*0.25f;
        }
    }

    const float* __restrict__ vbase = vbuf + ((long)bp * M) * HD + h * D;
    const float4* rm0 = (const float4*)&rmask[t0 * M];
    const float4* rm1 = (const float4*)&rmask[t1 * M];

    float sum0 = 0.f, sum1 = 0.f;
    float o0[16], o1[16];
    #pragma unroll
    for (int d = 0; d < 16; ++d) { o0[d] = 0.f; o1[d] = 0.f; }

    for (int mb = 0; mb < 32; ++mb) {          // NOT force-unrolled (VGPR!)
        float4 r0 = rm0[mb], r1 = rm1[mb];
        float r0v[4] = {r0.x, r0.y, r0.z, r0.w};
        float r1v[4] = {r1.x, r1.y, r1.z, r1.w};
        #pragma unroll
        for (int j = 0; j < 4; ++j) {
            const int m = mb * 4 + j;
            const float4* k4 = (const float4*)&kh[m][0];
            const float4* v4 = (const float4*)&vbase[(long)m * HD];  // scalar path
            float s0 = 0.f, s1 = 0.f;
            #pragma unroll
            for (int q4 = 0; q4 < 4; ++q4) {
                float4 kq = k4[q4];
                s0 += qr0[q4*4+0]*kq.x + qr0[q4*4+1]*kq.y
                    + qr0[q4*4+2]*kq.z + qr0[q4*4+3]*kq.w;
                s1 += qr1[q4*4+0]*kq.x + qr1[q4*4+1]*kq.y
                    + qr1[q4*4+2]*kq.z + qr1[q4*4+3]*kq.w;
            }
            float e0 = __expf(s0 + r0v[j]);
            float e1 = __expf(s1 + r1v[j]);
            sum0 += e0; sum1 += e1;
            #pragma unroll
            for (int q4 = 0; q4 < 4; ++q4) {
                float4 vq = v4[q4];
                o0[q4*4+0] += e0*vq.x; o0[q4*4+1] += e0*vq.y;
                o0[q4*4+2] += e0*vq.z; o0[q4*4+3] += e0*vq.w;
                o1[q4*4+0] += e1*vq.x; o1[q4*4+1] += e1*vq.y;
                o1[q4*4+2] += e1*vq.z; o1[q4*4+3] += e1*vq.w;
            }
        }
    }

    const float inv0 = ((ninf[t0] == 0.f) ? 1.f : 0.f) / sum0;
    const float inv1 = ((ninf[t1] == 0.f) ? 1.f : 0.f) / sum1;
    float* __restrict__ xb = xcatT + (long)bp * HD * N + (long)h * D * N;
    #pragma unroll
    for (int d = 0; d < 16; ++d) {
        xb[d * N + tid]      = o0[d] * inv0;
        xb[d * N + tid + 64] = o1[d] * inv1;
    }
}

// ---------------------------------------------------------------------------
// K3: MoE gating (top-2) + collapsed expert scoring + final softmax.
// grid BP, block 128. r11-EXACT (coalesced xcatT reads, two passes,
// f-ascending order, fused loss via last-block ticket).
// ---------------------------------------------------------------------------
__global__ __launch_bounds__(128) void moe_final_kernel(
    const float* __restrict__ xcatT,  // [BP][HD][N]
    const float* __restrict__ Wg,
    const float* __restrict__ ninf, const float* __restrict__ Wep,
    const float* __restrict__ bpv, float* __restrict__ importance,
    unsigned* __restrict__ ticket, float* __restrict__ out) {
    __shared__ float WgS[EMB][NE];   // 4 KB
    __shared__ float WeS[NE][132];   // padded
    __shared__ float red[N];
    __shared__ float impS[NE];

    const int bp = blockIdx.x;
    const int n  = threadIdx.x;

    #pragma unroll
    for (int i = 0; i < 2; ++i) {
        int e = n + i * 128;
        int r = e >> 1, c4 = (e & 1) * 4;
        *(float4*)&WgS[r][c4] = *(const float4*)&Wg[(long)r * NE + c4];
    }
    #pragma unroll
    for (int i = 0; i < 2; ++i) {
        int idx = n + i * 128;
        int r = idx >> 5, c = (idx & 31) * 4;
        *(float4*)&WeS[r][c] = *(const float4*)&Wep[(long)r * HD + c];
    }
    if (n < NE) impS[n] = 0.f;
    __syncthreads();

    const long t = (long)bp * N + n;
    const float* __restrict__ xrow = xcatT + (long)bp * HD * N;  // [f][n]

    float gl[NE];
    #pragma unroll
    for (int e = 0; e < NE; ++e) gl[e] = 0.f;
    for (int f = 0; f < HD; ++f) {           // f ascending: same sum order
        float xv = xrow[f * N + n];          // coalesced across n
        #pragma unroll
        for (int e = 0; e < NE; ++e) gl[e] += xv * WgS[f][e];
    }

    int e0 = 0; float v0 = gl[0];
    #pragma unroll
    for (int e = 1; e < NE; ++e) if (gl[e] > v0) { v0 = gl[e]; e0 = e; }
    int e1 = -1; float v1 = -3.4e38f;
    #pragma unroll
    for (int e = 0; e < NE; ++e) if (e != e0 && gl[e] > v1) { v1 = gl[e]; e1 = e; }
    float ex = __expf(v1 - v0);
    float g0 = 1.f / (1.f + ex);
    float g1 = ex / (1.f + ex);

    atomicAdd(&impS[e0], g0);
    atomicAdd(&impS[e1], g1);

    float s = g0 * bpv[e0] + g1 * bpv[e1];
    for (int f = 0; f < HD; ++f) {           // f ascending: same sum order
        float xv = xrow[f * N + n];          // coalesced, L2-hot
        s += xv * (g0 * WeS[e0][f] + g1 * WeS[e1][f]);
    }
    s = 10.f * tanhf(s) + ninf[t];

    red[n] = s;
    __syncthreads();
    for (int off = 64; off > 0; off >>= 1) {
        if (n < off) red[n] = fmaxf(red[n], red[n + off]);
        __syncthreads();
    }
    float mx = red[0];
    __syncthreads();
    float e = __expf(s - mx);
    red[n] = e;
    __syncthreads();
    for (int off = 64; off > 0; off >>= 1) {
        if (n < off) red[n] += red[n + off];
        __syncthreads();
    }
    float sum = red[0];

    out[t] = e / sum;

    if (n < NE) atomicAdd(&importance[n], impS[n]);

    // ---- fused moe_loss: last block to finish computes it ----
    __syncthreads();                 // drains this block's importance atomics
    if (n == 0) {
        __threadfence();
        unsigned tk = atomicAdd(ticket, 1u);
        if (tk == BP - 1) {          // all 400 blocks' atomics are visible
            __threadfence();
            float imp[NE];
            #pragma unroll
            for (int ei = 0; ei < NE; ++ei)
                imp[ei] = atomicAdd(&importance[ei], 0.f);  // coherent read
            float mean = 0.f;
            #pragma unroll
            for (int ei = 0; ei < NE; ++ei) mean += imp[ei];
            mean *= (1.f / NE);
            float var = 0.f;
            #pragma unroll
            for (int ei = 0; ei < NE; ++ei) {
                float d = imp[ei] - mean;
                var += d * d;
            }
            var *= (1.f / NE);
            out[T] = var / (mean * mean + 1e-10f);
        }
    }
}

// ---------------------------------------------------------------------------
extern "C" void kernel_launch(void* const* d_in, const int* in_sizes, int n_in,
                              void* d_out, int out_size, void* d_ws, size_t ws_size,
                              hipStream_t stream) {
    const float* nodes  = (const float*)d_in[0];
    const float* routes = (const float*)d_in[1];
    const float* ninf   = (const float*)d_in[2];
    const float* rmask  = (const float*)d_in[3];
    const float* Wq     = (const float*)d_in[4];
    const float* Wk     = (const float*)d_in[5];
    const float* Wv     = (const float*)d_in[6];
    const float* Wg     = (const float*)d_in[7];
    const float* We     = (const float*)d_in[8];
    const float* be     = (const float*)d_in[9];
    const float* Wfin   = (const float*)d_in[10];

    float* ws = (float*)d_ws;
    float* Wep        = ws + 16;
    float* bpv        = ws + 1040;
    float* importance = ws + 1048;
    unsigned* ticket  = (unsigned*)(ws + 1056);
    float* qbuf       = ws + 4096;
    float* kbuf       = qbuf + (long)T * HD;
    float* vbuf       = kbuf + (long)T * HD;
    float* xcatT      = vbuf + (long)T * HD;   // [BP][HD][N]

    float* out = (float*)d_out;

    proj_kernel<<<dim3(400, 3), 256, 0, stream>>>(nodes, routes, Wq, Wk, Wv,
                                                  qbuf, kbuf, vbuf,
                                                  We, be, Wfin, Wep, bpv,
                                                  importance, ticket);
    attn_kernel<<<dim3(BP, H), 64, 0, stream>>>(qbuf, kbuf, vbuf,
                                                rmask, ninf, xcatT);
    moe_final_kernel<<<BP, 128, 0, stream>>>(xcatT, Wg, ninf, Wep, bpv,
                                             importance, ticket, out);
}

// Round 14
// 286.143 us; speedup vs baseline: 1.2531x; 1.2531x over previous
//
#include <hip/hip_runtime.h>

constexpr int B  = 8,  P = 50, N = 128, M = 128;
constexpr int EMB = 128, H = 8, D = 16;
constexpr int NE = 8;
constexpr int HD = H * D;        // 128
constexpr int E1 = EMB + 1;      // 129
constexpr int BP = B * P;        // 400
constexpr int T  = BP * N;       // 51200 tokens

// ---------------------------------------------------------------------------
// K1: q/k/v projections (r7-proven) + FOLDED prep at blockIdx.y==3.
// grid (400, 4), block 256. r11-EXACT (281.2 us composition).
// r12/r13 lesson: k+v merge refuted — grid delivers ~3 blocks/CU so LDS
// was never the occupancy cap (r12's 41.5KB irrelevant), and the union fix
// introduced 1.2e7 bank conflicts (r13). Separate GEMMs win.
// ---------------------------------------------------------------------------
__global__ __launch_bounds__(256) void proj_kernel(
    const float* __restrict__ nodes,  // [T][128]
    const float* __restrict__ routes, // [T][129]
    const float* __restrict__ Wq, const float* __restrict__ Wk,
    const float* __restrict__ Wv,
    float* __restrict__ qo, float* __restrict__ ko, float* __restrict__ vo,
    const float* __restrict__ We, const float* __restrict__ be,
    const float* __restrict__ Wf,
    float* __restrict__ Wep, float* __restrict__ bpv,
    float* __restrict__ importance, unsigned* __restrict__ ticket) {
    const int mat = blockIdx.y;

    if (mat == 3) {                   // ---- folded prep ----
        const int e = blockIdx.x;
        if (e >= NE) return;
        const int f = threadIdx.x;
        if (f < HD) {
            float a = 0.f;
            const long base = ((long)e * HD + f) * E1;
            for (int o = 0; o < E1; ++o) a += We[base + o] * Wf[o];
            Wep[e * HD + f] = a;
        } else if (f == HD) {
            float b = 0.f;
            for (int o = 0; o < E1; ++o) b += be[(long)e * E1 + o] * Wf[o];
            bpv[e] = b;
        }
        if (e == 0) {
            if (f >= 140 && f < 140 + NE) importance[f - 140] = 0.f;
            if (f == 150) *ticket = 0u;
        }
        return;
    }

    const float* __restrict__ X = (mat == 0) ? nodes : routes;
    const float* __restrict__ W = (mat == 0) ? Wq : (mat == 1 ? Wk : Wv);
    float* __restrict__ out     = (mat == 0) ? qo : (mat == 1 ? ko : vo);
    const int Kd = (mat == 0) ? EMB : E1;
    const int nit = (Kd + 7) >> 3;

    const int row0 = blockIdx.x * 128;
    const int tid  = threadIdx.x;
    const int tr   = tid >> 4;        // 0..15
    const int tc   = tid & 15;        // 0..15

    __shared__ float XT[2][8][132];   // [buf][k][row], padded
    __shared__ float WS[2][8][132];   // [buf][k][col]

    float acc[8][8];
    #pragma unroll
    for (int i = 0; i < 8; ++i)
        #pragma unroll
        for (int j = 0; j < 8; ++j) acc[i][j] = 0.f;

    float xr[4];
    float4 wr;
    const int xkx = tid & 7, xrr = tid >> 3;          // +i*32 rows
    const int wkx = tid >> 5, wc4 = (tid & 31) * 4;

    {   // prologue: fetch tile 0
        #pragma unroll
        for (int i = 0; i < 4; ++i) {
            int kg = xkx;
            xr[i] = (kg < Kd) ? X[(long)(row0 + xrr + i * 32) * Kd + kg] : 0.f;
        }
        wr = (wkx < Kd) ? *(const float4*)&W[(long)wkx * HD + wc4]
                        : make_float4(0.f, 0.f, 0.f, 0.f);
        #pragma unroll
        for (int i = 0; i < 4; ++i) XT[0][xkx][xrr + i * 32] = xr[i];
        *(float4*)&WS[0][wkx][wc4] = wr;
    }
    __syncthreads();

    for (int it = 0; it < nit; ++it) {
        const int buf = it & 1;
        if (it + 1 < nit) {
            const int kk = (it + 1) * 8;
            #pragma unroll
            for (int i = 0; i < 4; ++i) {
                int kg = kk + xkx;
                xr[i] = (kg < Kd) ? X[(long)(row0 + xrr + i * 32) * Kd + kg] : 0.f;
            }
            int kg = kk + wkx;
            wr = (kg < Kd) ? *(const float4*)&W[(long)kg * HD + wc4]
                           : make_float4(0.f, 0.f, 0.f, 0.f);
        }

        #pragma unroll
        for (int k = 0; k < 8; ++k) {
            float4 xa = *(const float4*)&XT[buf][k][tr * 4];
            float4 xb = *(const float4*)&XT[buf][k][64 + tr * 4];
            float4 wa = *(const float4*)&WS[buf][k][tc * 4];
            float4 wb = *(const float4*)&WS[buf][k][64 + tc * 4];
            float xv[8] = {xa.x, xa.y, xa.z, xa.w, xb.x, xb.y, xb.z, xb.w};
            float wvv[8] = {wa.x, wa.y, wa.z, wa.w, wb.x, wb.y, wb.z, wb.w};
            #pragma unroll
            for (int i = 0; i < 8; ++i)
                #pragma unroll
                for (int j = 0; j < 8; ++j) acc[i][j] += xv[i] * wvv[j];
        }

        if (it + 1 < nit) {
            const int nb = buf ^ 1;
            #pragma unroll
            for (int i = 0; i < 4; ++i) XT[nb][xkx][xrr + i * 32] = xr[i];
            *(float4*)&WS[nb][wkx][wc4] = wr;
        }
        __syncthreads();
    }

    #pragma unroll
    for (int i = 0; i < 8; ++i) {
        int r = row0 + (i < 4 ? 0 : 64) + tr * 4 + (i & 3);
        float4 o0 = make_float4(acc[i][0], acc[i][1], acc[i][2], acc[i][3]);
        float4 o1 = make_float4(acc[i][4], acc[i][5], acc[i][6], acc[i][7]);
        *(float4*)&out[(long)r * HD + tc * 4]      = o0;
        *(float4*)&out[(long)r * HD + 64 + tc * 4] = o1;
    }
}

// ---------------------------------------------------------------------------
// K2: masked attention per (bp, head). grid (BP, 8), block 64 (1 wave).
// r11-EXACT (93.2 us, reproduced twice). FROZEN — 9 variants lost. h MUST
// stay blockIdx-derived (r10: scalar v-load path). Transposed stores.
// ---------------------------------------------------------------------------
__global__ __launch_bounds__(64) void attn_kernel(
    const float* __restrict__ qbuf,   // [T][128]
    const float* __restrict__ kbuf,   // [T][128]
    const float* __restrict__ vbuf,   // [T][128]
    const float* __restrict__ rmask,  // [BP*N][M]
    const float* __restrict__ ninf,   // [BP*N]
    float* __restrict__ xcatT) {      // [BP][HD][N] transposed!
    const int bp  = blockIdx.x;
    const int h   = blockIdx.y;       // MUST be blockIdx-derived (r10!)
    const int tid = threadIdx.x;

    __shared__ float kh[M][D];        // 8 KB (k only)

    #pragma unroll
    for (int i = 0; i < 8; ++i) {
        int e = tid + i * 64;         // f4 index 0..511
        int r = e >> 2, c4 = (e & 3) * 4;
        *(float4*)&kh[r][c4] = *(const float4*)&kbuf[((long)bp * M + r) * HD + h * D + c4];
    }
    __syncthreads();

    const long t0 = (long)bp * N + tid, t1 = t0 + 64;

    float qr0[16], qr1[16];
    {
        const float4* q0 = (const float4*)&qbuf[t0 * HD + h * D];
        const float4* q1 = (const float4*)&qbuf[t1 * HD + h * D];
        #pragma unroll
        for (int i = 0; i < 4; ++i) {
            float4 a = q0[i], b = q1[i];
            qr0[i*4+0] = a.x*0.25f; qr0[i*4+1] = a.y*0.25f;
            qr0[i*4+2] = a.z*0.25f; qr0[i*4+3] = a.w*0.25f;
            qr1[i*4+0] = b.x*0.25f; qr1[i*4+1] = b.y*0.25f;
            qr1[i*4+2] = b.z*0.25f; qr1[i*4+3] = b.w*0.25f;
        }
    }

    const float* __restrict__ vbase = vbuf + ((long)bp * M) * HD + h * D;
    const float4* rm0 = (const float4*)&rmask[t0 * M];
    const float4* rm1 = (const float4*)&rmask[t1 * M];

    float sum0 = 0.f, sum1 = 0.f;
    float o0[16], o1[16];
    #pragma unroll
    for (int d = 0; d < 16; ++d) { o0[d] = 0.f; o1[d] = 0.f; }

    for (int mb = 0; mb < 32; ++mb) {          // NOT force-unrolled (VGPR!)
        float4 r0 = rm0[mb], r1 = rm1[mb];
        float r0v[4] = {r0.x, r0.y, r0.z, r0.w};
        float r1v[4] = {r1.x, r1.y, r1.z, r1.w};
        #pragma unroll
        for (int j = 0; j < 4; ++j) {
            const int m = mb * 4 + j;
            const float4* k4 = (const float4*)&kh[m][0];
            const float4* v4 = (const float4*)&vbase[(long)m * HD];  // scalar path
            float s0 = 0.f, s1 = 0.f;
            #pragma unroll
            for (int q4 = 0; q4 < 4; ++q4) {
                float4 kq = k4[q4];
                s0 += qr0[q4*4+0]*kq.x + qr0[q4*4+1]*kq.y
                    + qr0[q4*4+2]*kq.z + qr0[q4*4+3]*kq.w;
                s1 += qr1[q4*4+0]*kq.x + qr1[q4*4+1]*kq.y
                    + qr1[q4*4+2]*kq.z + qr1[q4*4+3]*kq.w;
            }
            float e0 = __expf(s0 + r0v[j]);
            float e1 = __expf(s1 + r1v[j]);
            sum0 += e0; sum1 += e1;
            #pragma unroll
            for (int q4 = 0; q4 < 4; ++q4) {
                float4 vq = v4[q4];
                o0[q4*4+0] += e0*vq.x; o0[q4*4+1] += e0*vq.y;
                o0[q4*4+2] += e0*vq.z; o0[q4*4+3] += e0*vq.w;
                o1[q4*4+0] += e1*vq.x; o1[q4*4+1] += e1*vq.y;
                o1[q4*4+2] += e1*vq.z; o1[q4*4+3] += e1*vq.w;
            }
        }
    }

    const float inv0 = ((ninf[t0] == 0.f) ? 1.f : 0.f) / sum0;
    const float inv1 = ((ninf[t1] == 0.f) ? 1.f : 0.f) / sum1;
    float* __restrict__ xb = xcatT + (long)bp * HD * N + (long)h * D * N;
    #pragma unroll
    for (int d = 0; d < 16; ++d) {
        xb[d * N + tid]      = o0[d] * inv0;
        xb[d * N + tid + 64] = o1[d] * inv1;
    }
}

// ---------------------------------------------------------------------------
// K3: MoE gating (top-2) + collapsed expert scoring + final softmax.
// grid BP, block 128. r11-EXACT (coalesced xcatT reads, two passes,
// f-ascending order, fused loss via last-block ticket).
// ---------------------------------------------------------------------------
__global__ __launch_bounds__(128) void moe_final_kernel(
    const float* __restrict__ xcatT,  // [BP][HD][N]
    const float* __restrict__ Wg,
    const float* __restrict__ ninf, const float* __restrict__ Wep,
    const float* __restrict__ bpv, float* __restrict__ importance,
    unsigned* __restrict__ ticket, float* __restrict__ out) {
    __shared__ float WgS[EMB][NE];   // 4 KB
    __shared__ float WeS[NE][132];   // padded
    __shared__ float red[N];
    __shared__ float impS[NE];

    const int bp = blockIdx.x;
    const int n  = threadIdx.x;

    #pragma unroll
    for (int i = 0; i < 2; ++i) {
        int e = n + i * 128;
        int r = e >> 1, c4 = (e & 1) * 4;
        *(float4*)&WgS[r][c4] = *(const float4*)&Wg[(long)r * NE + c4];
    }
    #pragma unroll
    for (int i = 0; i < 2; ++i) {
        int idx = n + i * 128;
        int r = idx >> 5, c = (idx & 31) * 4;
        *(float4*)&WeS[r][c] = *(const float4*)&Wep[(long)r * HD + c];
    }
    if (n < NE) impS[n] = 0.f;
    __syncthreads();

    const long t = (long)bp * N + n;
    const float* __restrict__ xrow = xcatT + (long)bp * HD * N;  // [f][n]

    float gl[NE];
    #pragma unroll
    for (int e = 0; e < NE; ++e) gl[e] = 0.f;
    for (int f = 0; f < HD; ++f) {           // f ascending: same sum order
        float xv = xrow[f * N + n];          // coalesced across n
        #pragma unroll
        for (int e = 0; e < NE; ++e) gl[e] += xv * WgS[f][e];
    }

    int e0 = 0; float v0 = gl[0];
    #pragma unroll
    for (int e = 1; e < NE; ++e) if (gl[e] > v0) { v0 = gl[e]; e0 = e; }
    int e1 = -1; float v1 = -3.4e38f;
    #pragma unroll
    for (int e = 0; e < NE; ++e) if (e != e0 && gl[e] > v1) { v1 = gl[e]; e1 = e; }
    float ex = __expf(v1 - v0);
    float g0 = 1.f / (1.f + ex);
    float g1 = ex / (1.f + ex);

    atomicAdd(&impS[e0], g0);
    atomicAdd(&impS[e1], g1);

    float s = g0 * bpv[e0] + g1 * bpv[e1];
    for (int f = 0; f < HD; ++f) {           // f ascending: same sum order
        float xv = xrow[f * N + n];          // coalesced, L2-hot
        s += xv * (g0 * WeS[e0][f] + g1 * WeS[e1][f]);
    }
    s = 10.f * tanhf(s) + ninf[t];

    red[n] = s;
    __syncthreads();
    for (int off = 64; off > 0; off >>= 1) {
        if (n < off) red[n] = fmaxf(red[n], red[n + off]);
        __syncthreads();
    }
    float mx = red[0];
    __syncthreads();
    float e = __expf(s - mx);
    red[n] = e;
    __syncthreads();
    for (int off = 64; off > 0; off >>= 1) {
        if (n < off) red[n] += red[n + off];
        __syncthreads();
    }
    float sum = red[0];

    out[t] = e / sum;

    if (n < NE) atomicAdd(&importance[n], impS[n]);

    // ---- fused moe_loss: last block to finish computes it ----
    __syncthreads();                 // drains this block's importance atomics
    if (n == 0) {
        __threadfence();
        unsigned tk = atomicAdd(ticket, 1u);
        if (tk == BP - 1) {          // all 400 blocks' atomics are visible
            __threadfence();
            float imp[NE];
            #pragma unroll
            for (int ei = 0; ei < NE; ++ei)
                imp[ei] = atomicAdd(&importance[ei], 0.f);  // coherent read
            float mean = 0.f;
            #pragma unroll
            for (int ei = 0; ei < NE; ++ei) mean += imp[ei];
            mean *= (1.f / NE);
            float var = 0.f;
            #pragma unroll
            for (int ei = 0; ei < NE; ++ei) {
                float d = imp[ei] - mean;
                var += d * d;
            }
            var *= (1.f / NE);
            out[T] = var / (mean * mean + 1e-10f);
        }
    }
}

// ---------------------------------------------------------------------------
extern "C" void kernel_launch(void* const* d_in, const int* in_sizes, int n_in,
                              void* d_out, int out_size, void* d_ws, size_t ws_size,
                              hipStream_t stream) {
    const float* nodes  = (const float*)d_in[0];
    const float* routes = (const float*)d_in[1];
    const float* ninf   = (const float*)d_in[2];
    const float* rmask  = (const float*)d_in[3];
    const float* Wq     = (const float*)d_in[4];
    const float* Wk     = (const float*)d_in[5];
    const float* Wv     = (const float*)d_in[6];
    const float* Wg     = (const float*)d_in[7];
    const float* We     = (const float*)d_in[8];
    const float* be     = (const float*)d_in[9];
    const float* Wfin   = (const float*)d_in[10];

    float* ws = (float*)d_ws;
    float* Wep        = ws + 16;
    float* bpv        = ws + 1040;
    float* importance = ws + 1048;
    unsigned* ticket  = (unsigned*)(ws + 1056);
    float* qbuf       = ws + 4096;
    float* kbuf       = qbuf + (long)T * HD;
    float* vbuf       = kbuf + (long)T * HD;
    float* xcatT      = vbuf + (long)T * HD;   // [BP][HD][N]

    float* out = (float*)d_out;

    proj_kernel<<<dim3(400, 4), 256, 0, stream>>>(nodes, routes, Wq, Wk, Wv,
                                                  qbuf, kbuf, vbuf,
                                                  We, be, Wfin, Wep, bpv,
                                                  importance, ticket);
    attn_kernel<<<dim3(BP, H), 64, 0, stream>>>(qbuf, kbuf, vbuf,
                                                rmask, ninf, xcatT);
    moe_final_kernel<<<BP, 128, 0, stream>>>(xcatT, Wg, ninf, Wep, bpv,
                                             importance, ticket, out);
}